// Round 1
// 491.557 us; speedup vs baseline: 1.0190x; 1.0190x over previous
//
#include <hip/hip_runtime.h>
#include <math.h>

#define B 32
#define NQH 4
#define NKVH 2
#define HD 64
#define HIDDEN 256
#define QKV_DIM 512
#define MAX_SEQ 8192
#define PLANE (MAX_SEQ * HD)      // 524288 floats per (b,c,h) plane
#define SCALE 0.125f              // 1/sqrt(64)
#define CH 256                    // rows per chunk-block
#define NCH (MAX_SEQ / CH)        // 32 chunks per (b,h)
#define NEG_BIG -1e30f

// ws layout (floats):
//   q_rot   : [B][256]                    @ 0       (8192)
//   k_new   : [B][128]                    @ 8192    (4096)
//   v_new   : [B][128]                    @ 12288   (4096)
//   partials: [B*2][NCH] x 132 floats     @ 16384   (64*32*132 = 270336)
//             entry: {m[2], l[2], acc[2][64]}
#define WS_K    8192
#define WS_V    12288
#define WS_PART 16384

// Grid: B*2 blocks. half=0 computes the 4 q heads (256 outputs) + RoPE(q);
// half=1 computes k,v (256 outputs) + RoPE(k). One output row per thread.
__global__ __launch_bounds__(256) void qkv_rope_kernel(
    const float* __restrict__ x, const int* __restrict__ ctx_len,
    const float* __restrict__ rope, const float* __restrict__ qkv_w,
    const float* __restrict__ qkv_b, float* __restrict__ ws) {
    __shared__ float sx[HIDDEN];
    __shared__ float sv[HIDDEN];
    int bb = blockIdx.x;
    int b = bb >> 1, half = bb & 1;
    int tid = threadIdx.x;
    sx[tid] = x[b * HIDDEN + tid];
    __syncthreads();
    const float4* sx4 = (const float4*)sx;
    int e = half * 256 + tid;
    const float4* wrow = (const float4*)(qkv_w + e * HIDDEN);
    float acc = 0.f;
#pragma unroll 8
    for (int d4 = 0; d4 < HIDDEN / 4; ++d4) {
        float4 w = wrow[d4], xx = sx4[d4];
        acc += w.x * xx.x + w.y * xx.y + w.z * xx.z + w.w * xx.w;
    }
    sv[tid] = acc + qkv_b[e];
    __syncthreads();
    int pos = ctx_len[b];
    int nrot = half ? 64 : 128;   // q: 4 heads x 32 pairs; k: 2 heads x 32 pairs
    if (tid < nrot) {
        int which = tid >> 5, d = tid & 31;
        float c = rope[pos * HD + d];
        float s = rope[pos * HD + 32 + d];
        int base = which * HD;
        float t1 = sv[base + d], t2 = sv[base + 32 + d];
        sv[base + d] = t1 * c - t2 * s;
        sv[base + 32 + d] = t1 * s + t2 * c;
    }
    __syncthreads();
    if (half == 0) {
        ws[b * HIDDEN + tid] = sv[tid];                       // q
    } else if (tid < 128) {
        ws[WS_K + b * 128 + tid] = sv[tid];                   // k
    } else {
        ws[WS_V + b * 128 + (tid - 128)] = sv[tid];           // v
    }
}

// One block per (b, h, 256-row chunk): copies the K and V chunk from the
// input cache to the output cache, and computes the online-softmax partial
// for rows < pos from the same registers. Wave layout: 4 row-groups of
// 16 lanes; lane j holds float4 j of the row (16B coalesced).
__global__ __launch_bounds__(256) void fused_copy_attn(
    const float* __restrict__ kv_cache, const int* __restrict__ ctx_len,
    const float* __restrict__ ws, float* __restrict__ out_kv,
    float* __restrict__ partials) {
    int idx = blockIdx.x;
    int chunk = idx & (NCH - 1);
    int h = (idx >> 5) & 1;
    int b = idx >> 6;
    int pos = ctx_len[b];
    int start = chunk * CH;
    int tid = threadIdx.x;
    int w = tid >> 6, lane = tid & 63;
    int g = lane >> 4, j = lane & 15;
    size_t koff = ((size_t)(b * 2 + 0) * NKVH + h) * PLANE;
    size_t voff = ((size_t)(b * 2 + 1) * NKVH + h) * PLANE;
    const float4* kin = (const float4*)(kv_cache + koff);
    const float4* vin = (const float4*)(kv_cache + voff);
    float4* kout = (float4*)(out_kv + koff);
    float4* vout = (float4*)(out_kv + voff);
    float4 q0 = *(const float4*)(ws + b * HIDDEN + (h * 2 + 0) * HD + 4 * j);
    float4 q1 = *(const float4*)(ws + b * HIDDEN + (h * 2 + 1) * HD + 4 * j);
    float m0 = NEG_BIG, m1 = NEG_BIG, l0 = 0.f, l1 = 0.f;
    float4 a0 = {0, 0, 0, 0}, a1 = {0, 0, 0, 0};
#pragma unroll 4
    for (int i = 0; i < CH / 16; ++i) {
        int row = start + i * 16 + w * 4 + g;
        int fidx = row * 16 + j;
        float4 k4 = kin[fidx];
        float4 v4 = vin[fidx];
        kout[fidx] = k4;
        vout[fidx] = v4;
        if (row < pos) {
            float s0 = q0.x * k4.x + q0.y * k4.y + q0.z * k4.z + q0.w * k4.w;
            float s1 = q1.x * k4.x + q1.y * k4.y + q1.z * k4.z + q1.w * k4.w;
#pragma unroll
            for (int off = 1; off <= 8; off <<= 1) {
                s0 += __shfl_xor(s0, off);
                s1 += __shfl_xor(s1, off);
            }
            s0 *= SCALE; s1 *= SCALE;
            float nm0 = fmaxf(m0, s0);
            float al0 = __expf(m0 - nm0);
            float p0 = __expf(s0 - nm0);
            l0 = l0 * al0 + p0;
            a0.x = a0.x * al0 + p0 * v4.x; a0.y = a0.y * al0 + p0 * v4.y;
            a0.z = a0.z * al0 + p0 * v4.z; a0.w = a0.w * al0 + p0 * v4.w;
            m0 = nm0;
            float nm1 = fmaxf(m1, s1);
            float al1 = __expf(m1 - nm1);
            float p1 = __expf(s1 - nm1);
            l1 = l1 * al1 + p1;
            a1.x = a1.x * al1 + p1 * v4.x; a1.y = a1.y * al1 + p1 * v4.y;
            a1.z = a1.z * al1 + p1 * v4.z; a1.w = a1.w * al1 + p1 * v4.w;
            m1 = nm1;
        }
    }
    if (start >= pos) return;   // pure-copy block: no partial entry
    // merge the 4 row-groups within the wave (xor 16, then 32)
#pragma unroll
    for (int off = 16; off <= 32; off <<= 1) {
        float om0 = __shfl_xor(m0, off), ol0 = __shfl_xor(l0, off);
        float om1 = __shfl_xor(m1, off), ol1 = __shfl_xor(l1, off);
        float4 oa0, oa1;
        oa0.x = __shfl_xor(a0.x, off); oa0.y = __shfl_xor(a0.y, off);
        oa0.z = __shfl_xor(a0.z, off); oa0.w = __shfl_xor(a0.w, off);
        oa1.x = __shfl_xor(a1.x, off); oa1.y = __shfl_xor(a1.y, off);
        oa1.z = __shfl_xor(a1.z, off); oa1.w = __shfl_xor(a1.w, off);
        float M0 = fmaxf(m0, om0);
        float ea0 = __expf(m0 - M0), eb0 = __expf(om0 - M0);
        l0 = l0 * ea0 + ol0 * eb0;
        a0.x = a0.x * ea0 + oa0.x * eb0; a0.y = a0.y * ea0 + oa0.y * eb0;
        a0.z = a0.z * ea0 + oa0.z * eb0; a0.w = a0.w * ea0 + oa0.w * eb0;
        m0 = M0;
        float M1 = fmaxf(m1, om1);
        float ea1 = __expf(m1 - M1), eb1 = __expf(om1 - M1);
        l1 = l1 * ea1 + ol1 * eb1;
        a1.x = a1.x * ea1 + oa1.x * eb1; a1.y = a1.y * ea1 + oa1.y * eb1;
        a1.z = a1.z * ea1 + oa1.z * eb1; a1.w = a1.w * ea1 + oa1.w * eb1;
        m1 = M1;
    }
    __shared__ float sm[4][2], sl[4][2], sacc[4][2][64];
    if (lane < 16) {
        *(float4*)&sacc[w][0][4 * j] = a0;
        *(float4*)&sacc[w][1][4 * j] = a1;
        if (j == 0) { sm[w][0] = m0; sm[w][1] = m1; sl[w][0] = l0; sl[w][1] = l1; }
    }
    __syncthreads();
    if (tid < 128) {
        int gg = tid >> 6, d = tid & 63;
        float M = fmaxf(fmaxf(sm[0][gg], sm[1][gg]), fmaxf(sm[2][gg], sm[3][gg]));
        float L = 0.f, A = 0.f;
#pragma unroll
        for (int ww = 0; ww < 4; ++ww) {
            float e = __expf(sm[ww][gg] - M);
            L += sl[ww][gg] * e;
            A += sacc[ww][gg][d] * e;
        }
        float* ent = partials + (size_t)((b * 2 + h) * NCH + chunk) * 132;
        if (d == 0) { ent[gg] = M; ent[2 + gg] = L; }
        ent[4 + gg * 64 + d] = A;
    }
}

// Fused combine + output projection. One block per b, 256 threads.
// Thread tid = qh*64 + d  (qh = q-head = wave index, d = lane). The 64-lane
// shfl reduce computes the new-token score per head; the chunk-partial merge
// produces ctx[qh*64+d] into LDS; after one barrier the same 256 threads do
// the 256x256 output projection (1 row each).
__global__ __launch_bounds__(256) void combine_proj_kernel(
    const int* __restrict__ ctx_len, const float* __restrict__ ws,
    const float* __restrict__ out_w, float* __restrict__ out_kv,
    float* __restrict__ out) {
    int b = blockIdx.x;
    int tid = threadIdx.x;
    int qh = tid >> 6, d = tid & 63;
    int h = qh >> 1, g = qh & 1;
    int pos = ctx_len[b];
    // scatter the new-token k/v row into the output cache (after copy)
    {
        int kv = tid >> 7, hh = (tid >> 6) & 1, dd = tid & 63;
        float nv = ws[(kv ? WS_V : WS_K) + b * 128 + hh * HD + dd];
        out_kv[((size_t)(b * 2 + kv) * NKVH + hh) * PLANE + (size_t)pos * HD + dd] = nv;
    }
    float qv = ws[b * HIDDEN + qh * HD + d];
    float kn = ws[WS_K + b * 128 + h * HD + d];
    float vn = ws[WS_V + b * 128 + h * HD + d];
    float s = qv * kn;
#pragma unroll
    for (int off = 32; off; off >>= 1) s += __shfl_xor(s, off);
    s *= SCALE;
    int nch = (pos + CH - 1) / CH;
    const float* pbase = ws + WS_PART + (size_t)(b * 2 + h) * NCH * 132;
    float M = s;
    for (int c = 0; c < nch; ++c) M = fmaxf(M, pbase[c * 132 + g]);
    float e0 = __expf(s - M);
    float L = e0;
    float A = e0 * vn;
    for (int c = 0; c < nch; ++c) {
        const float* ent = pbase + c * 132;
        float e = __expf(ent[g] - M);
        L += ent[2 + g] * e;
        A += ent[4 + g * 64 + d] * e;
    }
    __shared__ float sc[HIDDEN];
    sc[tid] = A / L;            // ctx[b][qh*64+d]
    __syncthreads();
    const float4* wrow = (const float4*)(out_w + tid * HIDDEN);
    const float4* s4 = (const float4*)sc;
    float acc = 0.f;
#pragma unroll 8
    for (int d4 = 0; d4 < HIDDEN / 4; ++d4) {
        float4 w = wrow[d4], xx = s4[d4];
        acc += w.x * xx.x + w.y * xx.y + w.z * xx.z + w.w * xx.w;
    }
    out[b * HIDDEN + tid] = acc;
}

extern "C" void kernel_launch(void* const* d_in, const int* in_sizes, int n_in,
                              void* d_out, int out_size, void* d_ws, size_t ws_size,
                              hipStream_t stream) {
    const float* x = (const float*)d_in[0];
    const float* kv = (const float*)d_in[1];
    const int* cl = (const int*)d_in[2];
    const float* rope = (const float*)d_in[3];
    const float* qw = (const float*)d_in[4];
    const float* qb = (const float*)d_in[5];
    const float* ow = (const float*)d_in[6];
    float* out = (float*)d_out;
    float* out_kv = out + B * HIDDEN;
    float* ws = (float*)d_ws;

    qkv_rope_kernel<<<B * 2, 256, 0, stream>>>(x, cl, rope, qw, qb, ws);
    fused_copy_attn<<<B * NKVH * NCH, 256, 0, stream>>>(kv, cl, ws, out_kv, ws + WS_PART);
    combine_proj_kernel<<<B, 256, 0, stream>>>(cl, ws, ow, out_kv, out);
}

// Round 3
// 481.588 us; speedup vs baseline: 1.0401x; 1.0207x over previous
//
#include <hip/hip_runtime.h>
#include <math.h>

#define B 32
#define NQH 4
#define NKVH 2
#define HD 64
#define HIDDEN 256
#define QKV_DIM 512
#define MAX_SEQ 8192
#define PLANE (MAX_SEQ * HD)      // 524288 floats per (b,c,h) plane
#define SCALE 0.125f              // 1/sqrt(64)
#define CH 256                    // rows per chunk-block
#define NCH (MAX_SEQ / CH)        // 32 chunks per (b,h)
#define NEG_BIG -1e30f

// native 16B vector type usable with __builtin_nontemporal_* (HIP float4 is
// a struct and is rejected by the builtin). Layout-identical to float4.
typedef float f4 __attribute__((ext_vector_type(4)));

// ws layout (floats):
//   q_rot   : [B][256]                    @ 0       (8192)
//   k_new   : [B][128]                    @ 8192    (4096)
//   v_new   : [B][128]                    @ 12288   (4096)
//   partials: [B*2][NCH] x 132 floats     @ 16384   (64*32*132 = 270336)
//             entry: {m[2], l[2], acc[2][64]}
#define WS_K    8192
#define WS_V    12288
#define WS_PART 16384

// Grid: B*2 blocks. half=0 computes the 4 q heads (256 outputs) + RoPE(q);
// half=1 computes k,v (256 outputs) + RoPE(k). One output row per thread.
__global__ __launch_bounds__(256) void qkv_rope_kernel(
    const float* __restrict__ x, const int* __restrict__ ctx_len,
    const float* __restrict__ rope, const float* __restrict__ qkv_w,
    const float* __restrict__ qkv_b, float* __restrict__ ws) {
    __shared__ float sx[HIDDEN];
    __shared__ float sv[HIDDEN];
    int bb = blockIdx.x;
    int b = bb >> 1, half = bb & 1;
    int tid = threadIdx.x;
    sx[tid] = x[b * HIDDEN + tid];
    __syncthreads();
    const float4* sx4 = (const float4*)sx;
    int e = half * 256 + tid;
    const float4* wrow = (const float4*)(qkv_w + e * HIDDEN);
    float acc = 0.f;
#pragma unroll 8
    for (int d4 = 0; d4 < HIDDEN / 4; ++d4) {
        float4 w = wrow[d4], xx = sx4[d4];
        acc += w.x * xx.x + w.y * xx.y + w.z * xx.z + w.w * xx.w;
    }
    sv[tid] = acc + qkv_b[e];
    __syncthreads();
    int pos = ctx_len[b];
    int nrot = half ? 64 : 128;   // q: 4 heads x 32 pairs; k: 2 heads x 32 pairs
    if (tid < nrot) {
        int which = tid >> 5, d = tid & 31;
        float c = rope[pos * HD + d];
        float s = rope[pos * HD + 32 + d];
        int base = which * HD;
        float t1 = sv[base + d], t2 = sv[base + 32 + d];
        sv[base + d] = t1 * c - t2 * s;
        sv[base + 32 + d] = t1 * s + t2 * c;
    }
    __syncthreads();
    if (half == 0) {
        ws[b * HIDDEN + tid] = sv[tid];                       // q
    } else if (tid < 128) {
        ws[WS_K + b * 128 + tid] = sv[tid];                   // k
    } else {
        ws[WS_V + b * 128 + (tid - 128)] = sv[tid];           // v
    }
}

// One block per (b, h, 256-row chunk): copies the K and V chunk from the
// input cache to the output cache, and computes the online-softmax partial
// for rows < pos from the same registers. Wave layout: 4 row-groups of
// 16 lanes; lane j holds float4 j of the row (16B coalesced).
// Blocks entirely above pos take a dedicated tight streaming-copy path.
// All K/V traffic is touched exactly once -> nontemporal loads/stores.
__global__ __launch_bounds__(256) void fused_copy_attn(
    const float* __restrict__ kv_cache, const int* __restrict__ ctx_len,
    const float* __restrict__ ws, float* __restrict__ out_kv,
    float* __restrict__ partials) {
    int idx = blockIdx.x;
    int chunk = idx & (NCH - 1);
    int h = (idx >> 5) & 1;
    int b = idx >> 6;
    int pos = ctx_len[b];
    int start = chunk * CH;
    int tid = threadIdx.x;
    size_t koff = ((size_t)(b * 2 + 0) * NKVH + h) * PLANE;
    size_t voff = ((size_t)(b * 2 + 1) * NKVH + h) * PLANE;
    const f4* kin = (const f4*)(kv_cache + koff);
    const f4* vin = (const f4*)(kv_cache + voff);
    f4* kout = (f4*)(out_kv + koff);
    f4* vout = (f4*)(out_kv + voff);

    if (start >= pos) {
        // pure streaming copy: 256 rows x 16 float4 per plane, 16 iters
        int base = start * 16;
#pragma unroll
        for (int i = 0; i < 16; ++i) {
            int o = base + i * 256 + tid;
            f4 k4 = __builtin_nontemporal_load(&kin[o]);
            f4 v4 = __builtin_nontemporal_load(&vin[o]);
            __builtin_nontemporal_store(k4, &kout[o]);
            __builtin_nontemporal_store(v4, &vout[o]);
        }
        return;
    }

    int w = tid >> 6, lane = tid & 63;
    int g = lane >> 4, j = lane & 15;
    float4 q0 = *(const float4*)(ws + b * HIDDEN + (h * 2 + 0) * HD + 4 * j);
    float4 q1 = *(const float4*)(ws + b * HIDDEN + (h * 2 + 1) * HD + 4 * j);
    float m0 = NEG_BIG, m1 = NEG_BIG, l0 = 0.f, l1 = 0.f;
    float4 a0 = {0, 0, 0, 0}, a1 = {0, 0, 0, 0};
#pragma unroll 4
    for (int i = 0; i < CH / 16; ++i) {
        int row = start + i * 16 + w * 4 + g;
        int fidx = row * 16 + j;
        f4 k4 = __builtin_nontemporal_load(&kin[fidx]);
        f4 v4 = __builtin_nontemporal_load(&vin[fidx]);
        __builtin_nontemporal_store(k4, &kout[fidx]);
        __builtin_nontemporal_store(v4, &vout[fidx]);
        if (row < pos) {
            float s0 = q0.x * k4[0] + q0.y * k4[1] + q0.z * k4[2] + q0.w * k4[3];
            float s1 = q1.x * k4[0] + q1.y * k4[1] + q1.z * k4[2] + q1.w * k4[3];
#pragma unroll
            for (int off = 1; off <= 8; off <<= 1) {
                s0 += __shfl_xor(s0, off);
                s1 += __shfl_xor(s1, off);
            }
            s0 *= SCALE; s1 *= SCALE;
            float nm0 = fmaxf(m0, s0);
            float al0 = __expf(m0 - nm0);
            float p0 = __expf(s0 - nm0);
            l0 = l0 * al0 + p0;
            a0.x = a0.x * al0 + p0 * v4[0]; a0.y = a0.y * al0 + p0 * v4[1];
            a0.z = a0.z * al0 + p0 * v4[2]; a0.w = a0.w * al0 + p0 * v4[3];
            m0 = nm0;
            float nm1 = fmaxf(m1, s1);
            float al1 = __expf(m1 - nm1);
            float p1 = __expf(s1 - nm1);
            l1 = l1 * al1 + p1;
            a1.x = a1.x * al1 + p1 * v4[0]; a1.y = a1.y * al1 + p1 * v4[1];
            a1.z = a1.z * al1 + p1 * v4[2]; a1.w = a1.w * al1 + p1 * v4[3];
            m1 = nm1;
        }
    }
    // merge the 4 row-groups within the wave (xor 16, then 32)
#pragma unroll
    for (int off = 16; off <= 32; off <<= 1) {
        float om0 = __shfl_xor(m0, off), ol0 = __shfl_xor(l0, off);
        float om1 = __shfl_xor(m1, off), ol1 = __shfl_xor(l1, off);
        float4 oa0, oa1;
        oa0.x = __shfl_xor(a0.x, off); oa0.y = __shfl_xor(a0.y, off);
        oa0.z = __shfl_xor(a0.z, off); oa0.w = __shfl_xor(a0.w, off);
        oa1.x = __shfl_xor(a1.x, off); oa1.y = __shfl_xor(a1.y, off);
        oa1.z = __shfl_xor(a1.z, off); oa1.w = __shfl_xor(a1.w, off);
        float M0 = fmaxf(m0, om0);
        float ea0 = __expf(m0 - M0), eb0 = __expf(om0 - M0);
        l0 = l0 * ea0 + ol0 * eb0;
        a0.x = a0.x * ea0 + oa0.x * eb0; a0.y = a0.y * ea0 + oa0.y * eb0;
        a0.z = a0.z * ea0 + oa0.z * eb0; a0.w = a0.w * ea0 + oa0.w * eb0;
        m0 = M0;
        float M1 = fmaxf(m1, om1);
        float ea1 = __expf(m1 - M1), eb1 = __expf(om1 - M1);
        l1 = l1 * ea1 + ol1 * eb1;
        a1.x = a1.x * ea1 + oa1.x * eb1; a1.y = a1.y * ea1 + oa1.y * eb1;
        a1.z = a1.z * ea1 + oa1.z * eb1; a1.w = a1.w * ea1 + oa1.w * eb1;
        m1 = M1;
    }
    __shared__ float sm[4][2], sl[4][2], sacc[4][2][64];
    if (lane < 16) {
        *(float4*)&sacc[w][0][4 * j] = a0;
        *(float4*)&sacc[w][1][4 * j] = a1;
        if (j == 0) { sm[w][0] = m0; sm[w][1] = m1; sl[w][0] = l0; sl[w][1] = l1; }
    }
    __syncthreads();
    if (tid < 128) {
        int gg = tid >> 6, d = tid & 63;
        float M = fmaxf(fmaxf(sm[0][gg], sm[1][gg]), fmaxf(sm[2][gg], sm[3][gg]));
        float L = 0.f, A = 0.f;
#pragma unroll
        for (int ww = 0; ww < 4; ++ww) {
            float e = __expf(sm[ww][gg] - M);
            L += sl[ww][gg] * e;
            A += sacc[ww][gg][d] * e;
        }
        float* ent = partials + (size_t)((b * 2 + h) * NCH + chunk) * 132;
        if (d == 0) { ent[gg] = M; ent[2 + gg] = L; }
        ent[4 + gg * 64 + d] = A;
    }
}

// Fused combine + output projection. One block per b, 256 threads.
// Thread tid = qh*64 + d  (qh = q-head = wave index, d = lane). The 64-lane
// shfl reduce computes the new-token score per head; the chunk-partial merge
// produces ctx[qh*64+d] into LDS; after one barrier the same 256 threads do
// the 256x256 output projection (1 row each).
__global__ __launch_bounds__(256) void combine_proj_kernel(
    const int* __restrict__ ctx_len, const float* __restrict__ ws,
    const float* __restrict__ out_w, float* __restrict__ out_kv,
    float* __restrict__ out) {
    int b = blockIdx.x;
    int tid = threadIdx.x;
    int qh = tid >> 6, d = tid & 63;
    int h = qh >> 1, g = qh & 1;
    int pos = ctx_len[b];
    // scatter the new-token k/v row into the output cache (after copy)
    {
        int kv = tid >> 7, hh = (tid >> 6) & 1, dd = tid & 63;
        float nv = ws[(kv ? WS_V : WS_K) + b * 128 + hh * HD + dd];
        out_kv[((size_t)(b * 2 + kv) * NKVH + hh) * PLANE + (size_t)pos * HD + dd] = nv;
    }
    float qv = ws[b * HIDDEN + qh * HD + d];
    float kn = ws[WS_K + b * 128 + h * HD + d];
    float vn = ws[WS_V + b * 128 + h * HD + d];
    float s = qv * kn;
#pragma unroll
    for (int off = 32; off; off >>= 1) s += __shfl_xor(s, off);
    s *= SCALE;
    int nch = (pos + CH - 1) / CH;
    const float* pbase = ws + WS_PART + (size_t)(b * 2 + h) * NCH * 132;
    float M = s;
    for (int c = 0; c < nch; ++c) M = fmaxf(M, pbase[c * 132 + g]);
    float e0 = __expf(s - M);
    float L = e0;
    float A = e0 * vn;
    for (int c = 0; c < nch; ++c) {
        const float* ent = pbase + c * 132;
        float e = __expf(ent[g] - M);
        L += ent[2 + g] * e;
        A += ent[4 + g * 64 + d] * e;
    }
    __shared__ float sc[HIDDEN];
    sc[tid] = A / L;            // ctx[b][qh*64+d]
    __syncthreads();
    const float4* wrow = (const float4*)(out_w + tid * HIDDEN);
    const float4* s4 = (const float4*)sc;
    float acc = 0.f;
#pragma unroll 8
    for (int d4 = 0; d4 < HIDDEN / 4; ++d4) {
        float4 w = wrow[d4], xx = s4[d4];
        acc += w.x * xx.x + w.y * xx.y + w.z * xx.z + w.w * xx.w;
    }
    out[b * HIDDEN + tid] = acc;
}

extern "C" void kernel_launch(void* const* d_in, const int* in_sizes, int n_in,
                              void* d_out, int out_size, void* d_ws, size_t ws_size,
                              hipStream_t stream) {
    const float* x = (const float*)d_in[0];
    const float* kv = (const float*)d_in[1];
    const int* cl = (const int*)d_in[2];
    const float* rope = (const float*)d_in[3];
    const float* qw = (const float*)d_in[4];
    const float* qb = (const float*)d_in[5];
    const float* ow = (const float*)d_in[6];
    float* out = (float*)d_out;
    float* out_kv = out + B * HIDDEN;
    float* ws = (float*)d_ws;

    qkv_rope_kernel<<<B * 2, 256, 0, stream>>>(x, cl, rope, qw, qb, ws);
    fused_copy_attn<<<B * NKVH * NCH, 256, 0, stream>>>(kv, cl, ws, out_kv, ws + WS_PART);
    combine_proj_kernel<<<B, 256, 0, stream>>>(cl, ws, ow, out_kv, out);
}